// Round 13
// baseline (1255.587 us; speedup 1.0000x reference)
//
#include <hip/hip_runtime.h>
#include <hip/hip_bf16.h>

#define B_ 128
#define L_ 2048
#define D_ 256
#define H_ 512
#define U_ 256

typedef _Float16 half8 __attribute__((ext_vector_type(8)));
typedef float f32x4 __attribute__((ext_vector_type(4)));

// ---------------------------------------------------------------------------
// Kernel PA (fused): blocks 0..31: W1 split; blocks 32..159: proj_h.
// W1 [D][U] fp32 -> slot-major halves W1s[slot=k/8][u][k%8], x = hi + lo
// (22 effective mantissa bits; full 3-pass consumption restores the
// 1.2207e-4 absmax measured for the fp32 and 3-pass kernels).
// ---------------------------------------------------------------------------
__global__ __launch_bounds__(256) void kpa_prep(
    const float* __restrict__ W1, _Float16* __restrict__ hi,
    _Float16* __restrict__ lo, const float* __restrict__ hidden,
    const float* __restrict__ W2, const float* __restrict__ b1,
    const float* __restrict__ b2, float* __restrict__ ph) {
  __shared__ float hs[H_];
  if (blockIdx.x < 32) {
    int slot = blockIdx.x;  // D_/8 = 32
    int u = threadIdx.x;
    union { _Float16 h[8]; float4 f; } H, Lo;
#pragma unroll
    for (int j = 0; j < 8; ++j) {
      float x = W1[(slot * 8 + j) * U_ + u];
      _Float16 h = (_Float16)x;
      H.h[j] = h;
      Lo.h[j] = (_Float16)(x - (float)h);
    }
    *(float4*)&hi[((size_t)slot * U_ + u) * 8] = H.f;
    *(float4*)&lo[((size_t)slot * U_ + u) * 8] = Lo.f;
  } else {
    int b = blockIdx.x - 32;
    int u = threadIdx.x;
    for (int k = u; k < H_; k += 256) hs[k] = hidden[b * H_ + k];
    __syncthreads();
    float acc = b1[u] + b2[u];
#pragma unroll 8
    for (int k = 0; k < H_; ++k) acc += hs[k] * W2[k * U_ + u];
    ph[b * U_ + u] = acc;
  }
}

// ---------------------------------------------------------------------------
// Kernel B (MFMA, 3-pass): logits = sum_u tanh(F·W1 + ph) * V
// 512 thr = 8 waves, tile 128x256; wave (wr,wc) owns 64x64. K chunks of 32.
// OCCUPANCY: __launch_bounds__(512,6) caps VGPR at 85 -> 6 waves/SIMD ->
// 3 blocks/CU (LDS 48KB x 3 = 144KB). Reg-prefetch carried across MFMA is
// trimmed to a0,a1,h0,h1 (16 regs); B-lo (q0,q1) is loaded from L2 inside
// the conv window (W1s chunk is L2-hot; ~200cy stall covered by 24 waves).
// Slot-major LDS: measured 0 bank conflicts (round 7).
// ---------------------------------------------------------------------------
#define TLM 128
#define BKC 32
#define NCH (D_ / BKC)  // 8 chunks

__global__ __launch_bounds__(512, 6) void kb_mfma(
    const float* __restrict__ features, const _Float16* __restrict__ W1s_hi,
    const _Float16* __restrict__ W1s_lo, const float* __restrict__ ph,
    const float* __restrict__ V, float* __restrict__ logits) {
  __shared__ __align__(16) char smem[49152];  // 48 KB
  _Float16(*Ah)[TLM][8] = (_Float16(*)[TLM][8])(smem);          // 8 KB
  _Float16(*Al)[TLM][8] = (_Float16(*)[TLM][8])(smem + 8192);   // 8 KB
  _Float16* Bh = (_Float16*)(smem + 16384);                     // 16 KB
  _Float16* Bl = (_Float16*)(smem + 32768);                     // 16 KB
  float(*red)[TLM] = (float(*)[TLM])(smem);  // aliases Ah after final chunk

  const int tid = threadIdx.x;
  const int w = tid >> 6;
  const int lane = tid & 63;
  const int g = lane >> 4;
  const int c = lane & 15;
  const int wr = w >> 2;
  const int wc = w & 3;
  const int b = blockIdx.x >> 4;  // 16 row-tiles per batch
  const int l0 = (blockIdx.x & 15) * TLM;
  const float* fbase = features + ((size_t)b * L_ + l0) * D_;

  // A staging: thread -> (row ar, k-slot ag), 8 fp32 = 32 B contiguous.
  const int ar = tid & 127;
  const int ag = tid >> 7;
  const float* aptr = fbase + (size_t)ar * D_ + ag * 8;

#define CONV_WRITE_A(a0, a1)                                                \
  do {                                                                      \
    union { _Float16 h[8]; float4 f; } Hh, Ll;                              \
    Hh.h[0] = (_Float16)a0.x; Ll.h[0] = (_Float16)(a0.x - (float)Hh.h[0]);  \
    Hh.h[1] = (_Float16)a0.y; Ll.h[1] = (_Float16)(a0.y - (float)Hh.h[1]);  \
    Hh.h[2] = (_Float16)a0.z; Ll.h[2] = (_Float16)(a0.z - (float)Hh.h[2]);  \
    Hh.h[3] = (_Float16)a0.w; Ll.h[3] = (_Float16)(a0.w - (float)Hh.h[3]);  \
    Hh.h[4] = (_Float16)a1.x; Ll.h[4] = (_Float16)(a1.x - (float)Hh.h[4]);  \
    Hh.h[5] = (_Float16)a1.y; Ll.h[5] = (_Float16)(a1.y - (float)Hh.h[5]);  \
    Hh.h[6] = (_Float16)a1.z; Ll.h[6] = (_Float16)(a1.z - (float)Hh.h[6]);  \
    Hh.h[7] = (_Float16)a1.w; Ll.h[7] = (_Float16)(a1.w - (float)Hh.h[7]);  \
    *(float4*)&Ah[ag][ar][0] = Hh.f;                                        \
    *(float4*)&Al[ag][ar][0] = Ll.f;                                        \
  } while (0)

  f32x4 acc[4][4];
#pragma unroll
  for (int mt = 0; mt < 4; ++mt)
#pragma unroll
    for (int nt = 0; nt < 4; ++nt) acc[mt][nt] = (f32x4){0.f, 0.f, 0.f, 0.f};

  // ---- prolog: stage chunk 0 (B-lo loaded and written directly) ----
  {
    float4 a0 = *(const float4*)(aptr);
    float4 a1 = *(const float4*)(aptr + 4);
    float4 h0 = *(const float4*)&W1s_hi[(size_t)tid * 8];
    float4 h1 = *(const float4*)&W1s_hi[(size_t)(tid + 512) * 8];
    float4 q0 = *(const float4*)&W1s_lo[(size_t)tid * 8];
    float4 q1 = *(const float4*)&W1s_lo[(size_t)(tid + 512) * 8];
    CONV_WRITE_A(a0, a1);
    *(float4*)&Bh[(size_t)tid * 8] = h0;
    *(float4*)&Bh[(size_t)(tid + 512) * 8] = h1;
    *(float4*)&Bl[(size_t)tid * 8] = q0;
    *(float4*)&Bl[(size_t)(tid + 512) * 8] = q1;
  }
  __syncthreads();

#pragma unroll
  for (int t = 0; t < NCH; ++t) {
    float4 a0, a1, h0, h1;
    if (t < NCH - 1) {  // prefetch carried across MFMA: 16 VGPRs only
      const size_t roff = (size_t)(t + 1) * 8192;  // halves per chunk region
      a0 = *(const float4*)(aptr + (t + 1) * BKC);
      a1 = *(const float4*)(aptr + (t + 1) * BKC + 4);
      h0 = *(const float4*)&W1s_hi[roff + (size_t)tid * 8];
      h1 = *(const float4*)&W1s_hi[roff + (size_t)(tid + 512) * 8];
    }

    // fragments (slot-major, conflict-free)
    half8 ah[4], al[4], bh[4], bl[4];
#pragma unroll
    for (int mt = 0; mt < 4; ++mt) {
      ah[mt] = *(const half8*)&Ah[g][wr * 64 + mt * 16 + c][0];
      al[mt] = *(const half8*)&Al[g][wr * 64 + mt * 16 + c][0];
    }
#pragma unroll
    for (int nt = 0; nt < 4; ++nt) {
      const int u = wc * 64 + nt * 16 + c;
      bh[nt] = *(const half8*)&Bh[((size_t)g * U_ + u) * 8];
      bl[nt] = *(const half8*)&Bl[((size_t)g * U_ + u) * 8];
    }
    // 3 passes; dependent MFMAs on the same acc are 16 instructions apart
#pragma unroll
    for (int nt = 0; nt < 4; ++nt)
#pragma unroll
      for (int mt = 0; mt < 4; ++mt)
        acc[mt][nt] = __builtin_amdgcn_mfma_f32_16x16x32_f16(ah[mt], bh[nt],
                                                             acc[mt][nt], 0, 0, 0);
#pragma unroll
    for (int nt = 0; nt < 4; ++nt)
#pragma unroll
      for (int mt = 0; mt < 4; ++mt)
        acc[mt][nt] = __builtin_amdgcn_mfma_f32_16x16x32_f16(ah[mt], bl[nt],
                                                             acc[mt][nt], 0, 0, 0);
#pragma unroll
    for (int nt = 0; nt < 4; ++nt)
#pragma unroll
      for (int mt = 0; mt < 4; ++mt)
        acc[mt][nt] = __builtin_amdgcn_mfma_f32_16x16x32_f16(al[mt], bh[nt],
                                                             acc[mt][nt], 0, 0, 0);

    __syncthreads();  // everyone done reading tile t
    if (t < NCH - 1) {
      // B-lo: issue L2 loads first, hide under the conv VALU work
      const size_t roff = (size_t)(t + 1) * 8192;
      float4 q0 = *(const float4*)&W1s_lo[roff + (size_t)tid * 8];
      float4 q1 = *(const float4*)&W1s_lo[roff + (size_t)(tid + 512) * 8];
      CONV_WRITE_A(a0, a1);  // a/h landed during MFMA phase
      *(float4*)&Bh[(size_t)tid * 8] = h0;
      *(float4*)&Bh[(size_t)(tid + 512) * 8] = h1;
      *(float4*)&Bl[(size_t)tid * 8] = q0;
      *(float4*)&Bl[(size_t)(tid + 512) * 8] = q1;
      __syncthreads();  // tile t+1 ready
    }
  }

  // epilogue: tanh + V-dot. C layout: col=lane&15, row=(lane>>4)*4+reg.
  float phv[4], vv[4];
#pragma unroll
  for (int nt = 0; nt < 4; ++nt) {
    int col = wc * 64 + nt * 16 + c;
    phv[nt] = ph[b * U_ + col];
    vv[nt] = V[col];
  }
#pragma unroll
  for (int mt = 0; mt < 4; ++mt) {
#pragma unroll
    for (int j = 0; j < 4; ++j) {
      float part = 0.f;
#pragma unroll
      for (int nt = 0; nt < 4; ++nt) {
        float x = acc[mt][nt][j] + phv[nt];
        float e = __expf(2.f * x);
        float tnh = 1.f - 2.f * __builtin_amdgcn_rcpf(e + 1.f);  // tanh, inf-safe
        part += tnh * vv[nt];
      }
      part += __shfl_xor(part, 1, 16);
      part += __shfl_xor(part, 2, 16);
      part += __shfl_xor(part, 4, 16);
      part += __shfl_xor(part, 8, 16);
      // red aliases Ah: safe, all frag reads are behind the last barrier
      if (c == 0) red[wc][wr * 64 + mt * 16 + g * 4 + j] = part;
    }
  }
  __syncthreads();
  if (tid < TLM) {
    logits[b * L_ + l0 + tid] =
        red[0][tid] + red[1][tid] + red[2][tid] + red[3][tid];
  }
#undef CONV_WRITE_A
}

// ---------------------------------------------------------------------------
// Kernel C: softmax over L per batch; writes attention weights to d_out
// ---------------------------------------------------------------------------
__global__ __launch_bounds__(256) void kc_softmax(
    const float* __restrict__ logits, float* __restrict__ wout) {
  int b = blockIdx.x;
  int tid = threadIdx.x;
  const float* lrow = logits + b * L_;
  float v[8];
  *(float4*)&v[0] = *(const float4*)&lrow[tid * 8];
  *(float4*)&v[4] = *(const float4*)&lrow[tid * 8 + 4];

  float m = v[0];
#pragma unroll
  for (int i = 1; i < 8; ++i) m = fmaxf(m, v[i]);
#pragma unroll
  for (int off = 1; off <= 32; off <<= 1) m = fmaxf(m, __shfl_xor(m, off, 64));
  __shared__ float sm[4];
  if ((tid & 63) == 0) sm[tid >> 6] = m;
  __syncthreads();
  m = fmaxf(fmaxf(sm[0], sm[1]), fmaxf(sm[2], sm[3]));

  float s = 0.f;
#pragma unroll
  for (int i = 0; i < 8; ++i) {
    v[i] = __expf(v[i] - m);
    s += v[i];
  }
#pragma unroll
  for (int off = 1; off <= 32; off <<= 1) s += __shfl_xor(s, off, 64);
  __shared__ float ss[4];
  if ((tid & 63) == 0) ss[tid >> 6] = s;
  __syncthreads();
  s = ss[0] + ss[1] + ss[2] + ss[3];

  float inv = 1.f / s;
#pragma unroll
  for (int i = 0; i < 8; ++i) v[i] *= inv;
  *(float4*)&wout[b * L_ + tid * 8] = *(float4*)&v[0];
  *(float4*)&wout[b * L_ + tid * 8 + 4] = *(float4*)&v[4];
}

// ---------------------------------------------------------------------------
// Kernel D: partials[b][chunk][d] = sum_{l in chunk of 256} w[l]*f[l][d]
// ---------------------------------------------------------------------------
__global__ __launch_bounds__(256) void kd_partial(
    const float* __restrict__ features, const float* __restrict__ w,
    float* __restrict__ partials) {
  int bidx = blockIdx.x;  // B*8
  int b = bidx >> 3;
  int chunk = bidx & 7;
  int tid = threadIdx.x;
  int lq = tid >> 6;
  int dq = tid & 63;
  __shared__ float wsm[256];
  wsm[tid] = w[b * L_ + chunk * 256 + tid];
  __syncthreads();
  const float* fb =
      features + ((size_t)b * L_ + chunk * 256 + lq * 64) * D_ + dq * 4;
  const float* wl = &wsm[lq * 64];
  float4 acc = {0.f, 0.f, 0.f, 0.f};
#pragma unroll 8
  for (int i = 0; i < 64; ++i) {
    float wt = wl[i];
    float4 fv = *(const float4*)(fb + (size_t)i * D_);
    acc.x += wt * fv.x;
    acc.y += wt * fv.y;
    acc.z += wt * fv.z;
    acc.w += wt * fv.w;
  }
  __shared__ float red[4][256];
  *(float4*)&red[lq][dq * 4] = acc;
  __syncthreads();
  float ssum = red[0][tid] + red[1][tid] + red[2][tid] + red[3][tid];
  partials[(size_t)(b * 8 + chunk) * 256 + tid] = ssum;
}

// ---------------------------------------------------------------------------
// Kernel E: context[b][d] = sum_c partials[b][c][d]
// ---------------------------------------------------------------------------
__global__ __launch_bounds__(256) void ke_reduce(
    const float* __restrict__ partials, float* __restrict__ ctx) {
  int b = blockIdx.x;
  int d = threadIdx.x;
  float s = 0.f;
#pragma unroll
  for (int c = 0; c < 8; ++c) s += partials[(size_t)(b * 8 + c) * 256 + d];
  ctx[b * 256 + d] = s;
}

// ---------------------------------------------------------------------------
extern "C" void kernel_launch(void* const* d_in, const int* in_sizes, int n_in,
                              void* d_out, int out_size, void* d_ws,
                              size_t ws_size, hipStream_t stream) {
  const float* features = (const float*)d_in[0];
  const float* hidden = (const float*)d_in[1];
  const float* W1 = (const float*)d_in[2];
  const float* b1 = (const float*)d_in[3];
  const float* W2 = (const float*)d_in[4];
  const float* b2 = (const float*)d_in[5];
  const float* V = (const float*)d_in[6];
  // d_in[7] = bV: softmax shift-invariant, logits not returned -> dropped.

  float* ws = (float*)d_ws;
  float* ph = ws;                              // 32768 floats
  float* logits = ws + 32768;                  // 262144 floats
  float* partials = ws + 32768 + 262144;       // 262144 floats
  _Float16* W1s_hi = (_Float16*)(ws + 557056); // 65536 halves (slot-major)
  _Float16* W1s_lo = W1s_hi + 65536;           // 65536 halves

  float* ctx = (float*)d_out;             // [B, D]
  float* wout = (float*)d_out + B_ * D_;  // [B, L, 1]

  kpa_prep<<<32 + B_, 256, 0, stream>>>(W1, W1s_hi, W1s_lo, hidden, W2, b1, b2,
                                        ph);
  kb_mfma<<<B_ * (L_ / TLM), 512, 0, stream>>>(features, W1s_hi, W1s_lo, ph, V,
                                               logits);
  kc_softmax<<<B_, 256, 0, stream>>>(logits, wout);
  kd_partial<<<B_ * 8, 256, 0, stream>>>(features, wout, partials);
  ke_reduce<<<B_, 256, 0, stream>>>(partials, ctx);
}